// Round 13
// baseline (211.687 us; speedup 1.0000x reference)
//
#include <hip/hip_runtime.h>
#include <hip/hip_bf16.h>
#include <math.h>

// Problem: B=4, C=256, H=W=64 (N=4096), IC=128. I/O float32.
// R21: non-temporal cache policy on single-consumer cross-kernel traffic.
//     Differencing across R12/R15/R17/R18 pins the opart->wy path at 36-44us
//     in THREE different reader implementations (roofline ~7us) — the cost is
//     the WRITER's: flash leaves 33MB dirty in per-XCD L2s, consumed cross-XCD
//     (non-coherent) -> dirty-writeback on the consumer/boundary critical path.
//     (1) flash: nt stores for opart. (2) wy: nt loads for opart. (3) bn: nt
//     load x / nt store out. projf/gT stay cached (flash re-reads them ~40x).
//     Everything else R20-byte-identical (flash 4-wave, proj z-split, 5 disp).
typedef unsigned short ushort_t;
typedef __attribute__((ext_vector_type(8))) short     short8;   // bf16x8 MFMA frag
typedef __attribute__((ext_vector_type(8))) _Float16  half8;    // f16x8 MFMA frag
typedef __attribute__((ext_vector_type(8))) unsigned short ushort8;
typedef __attribute__((ext_vector_type(4))) float     float4v;
typedef __attribute__((ext_vector_type(16))) float    floatx16; // 32x32 acc

__device__ __forceinline__ float b2f(ushort_t u) {
    return __uint_as_float(((unsigned)u) << 16);
}
__device__ __forceinline__ ushort_t f2b(float f) {
    unsigned i = __float_as_uint(f);
    return (ushort_t)((i + 0x7FFFu + ((i >> 16) & 1u)) >> 16);  // RNE
}
__device__ __forceinline__ void split2(float v, ushort_t& h, ushort_t& l) {
    h = f2b(v);
    l = f2b(v - b2f(h));   // combined rel err ~2^-17
}
__device__ __forceinline__ void glds16(const ushort_t* g, ushort_t* l) {
    __builtin_amdgcn_global_load_lds((const __attribute__((address_space(1))) void*)g,
                                     (__attribute__((address_space(3))) void*)l, 16, 0, 0);
}
__device__ __forceinline__ unsigned int pack2bf(float lo, float hi) {
    unsigned int r;
    asm("v_cvt_pk_bf16_f32 %0, %1, %2" : "=v"(r) : "v"(lo), "v"(hi));
    return r;
}
// v_permlane32_swap_b32: a[32+i] <-> b[i]. After: a=[a.lo, b.lo_old], b=[a.hi_old, b.hi]
__device__ __forceinline__ void pl32swap(unsigned int& a, unsigned int& b) {
    asm("v_permlane32_swap_b32 %0, %1" : "+v"(a), "+v"(b));
}

// ---- workspace layout (bytes) ----
#define WTFH_OFF   0            // 192 KB proj weights B-frag hi
#define WTFL_OFF   196608       // 192 KB lo
#define WWBH_OFF   393216       // 64 KB w_w bf16 hi
#define WWBL_OFF   458752       // 64 KB lo
#define BIAS_OFF   524288       // 384 f32
#define PROJF_OFF  1048576      // 8 MB fp16 (theta|phi) [b][n][256]
#define GT_OFF     9437184      // 4 MB bf16 g transposed [b][ic][n]
#define OPART_OFF  13631488     // KQ*8 MB f32 partial O; oml after
#define WY_OFF     1048576      // wy bf16 reuses projf region (dead after flash)
#define PART_OFF   9437184      // 2 MB stats partials reuse gT region (dead after flash)

__global__ void prep_k(const float* __restrict__ dx_w, const float* __restrict__ dy_w,
                       const float* __restrict__ g_w,  const float* __restrict__ dx_b,
                       const float* __restrict__ dy_b, const float* __restrict__ g_b,
                       const float* __restrict__ w_w,
                       ushort_t* __restrict__ wtfh, ushort_t* __restrict__ wtfl,
                       ushort_t* __restrict__ wwbh, ushort_t* __restrict__ wwbl,
                       float* __restrict__ bias) {
    int idx = blockIdx.x * 256 + threadIdx.x;          // 0..98303
    int j = idx & 7, lane = (idx >> 3) & 63, kk = (idx >> 9) & 7, ot = idx >> 12;
    int o = ot * 16 + (lane & 15);
    int c = kk * 32 + ((lane >> 4) * 8) + j;
    float v;
    if (o < 128)      v = dx_w[o * 256 + c];
    else if (o < 256) v = dy_w[(o - 128) * 256 + c];
    else              v = g_w[(o - 256) * 256 + c];
    ushort_t h, l;
    split2(v, h, l);
    wtfh[idx] = h; wtfl[idx] = l;
    if (idx < 32768) {                                 // w_w [256][128]
        split2(w_w[idx], h, l);
        wwbh[idx] = h; wwbl[idx] = l;
    }
    if (idx < 384) {
        bias[idx] = (idx < 128) ? dx_b[idx]
                  : (idx < 256) ? dy_b[idx - 128]
                                : g_b[idx - 256];
    }
}

// ============================================================================
// Kernel 2: projections. s (source select) on blockIdx.z — grid 128x4x2, 1024
// blocks, 4 blocks/CU (33KB LDS). Each block: stage its source tile ->
// barrier -> MFMA. xT row stride 258 breaks ds_write_b16 bank conflicts.
// ============================================================================
#define XTS 258
__global__ __launch_bounds__(256) void proj_k(const float* __restrict__ x,
                                              const float* __restrict__ y,
                                              const ushort_t* __restrict__ wtfh,
                                              const ushort_t* __restrict__ wtfl,
                                              const float* __restrict__ bias,
                                              ushort_t* __restrict__ projf,
                                              ushort_t* __restrict__ gT) {
    __shared__ ushort_t xT[2][32 * XTS];   // [hi/lo][n][c], ~33KB
    int b = blockIdx.y, n0 = blockIdx.x * 32;
    int s = blockIdx.z;
    int tid = threadIdx.x;
    int w = tid >> 6, lane = tid & 63;
    int mrow = lane & 15, quad = lane >> 4, koff = quad * 8;
    int half = w & 1, sect = w >> 1;
    int arow = half * 16 + mrow;

    const float* src = s ? y : x;
    #pragma unroll
    for (int i = 0; i < 4; i++) {
        int ch = tid + i * 256;
        int c = ch >> 2, off = (ch & 3) * 8;
        const float* p = src + (size_t)(b * 256 + c) * 4096 + n0 + off;
        float4v v0 = *(const float4v*)p;
        float4v v1 = *(const float4v*)(p + 4);
        #pragma unroll
        for (int jj = 0; jj < 4; jj++) {
            ushort_t h, l;
            split2(v0[jj], h, l);
            xT[0][(off + jj) * XTS + c] = h;
            xT[1][(off + jj) * XTS + c] = l;
            split2(v1[jj], h, l);
            xT[0][(off + 4 + jj) * XTS + c] = h;
            xT[1][(off + 4 + jj) * XTS + c] = l;
        }
    }
    __syncthreads();

    short8 fh[8], fl[8];
    #pragma unroll
    for (int kk = 0; kk < 8; kk++) {
        fh[kk] = *(const short8*)&xT[0][arow * XTS + kk * 32 + koff];
        fl[kk] = *(const short8*)&xT[1][arow * XTS + kk * 32 + koff];
    }

    int ot0 = s ? (8 + sect * 8) : (sect * 4);
    int ot1 = s ? (ot0 + 8) : (ot0 + 4);
    for (int ot = ot0; ot < ot1; ot++) {
        float4v acc = {0.f, 0.f, 0.f, 0.f};
        #pragma unroll
        for (int kk = 0; kk < 8; kk++) {
            short8 bh = *(const short8*)(wtfh + (size_t)((ot * 8 + kk) * 64 + lane) * 8);
            short8 bl = *(const short8*)(wtfl + (size_t)((ot * 8 + kk) * 64 + lane) * 8);
            acc = __builtin_amdgcn_mfma_f32_16x16x32_bf16(fh[kk], bh, acc, 0, 0, 0);
            acc = __builtin_amdgcn_mfma_f32_16x16x32_bf16(fh[kk], bl, acc, 0, 0, 0);
            acc = __builtin_amdgcn_mfma_f32_16x16x32_bf16(fl[kk], bh, acc, 0, 0, 0);
        }
        int o = ot * 16 + mrow;                  // C/D: col = lane&15
        float bo = bias[o];
        #pragma unroll
        for (int r = 0; r < 4; r++) {
            int n = n0 + half * 16 + quad * 4 + r;  // C/D: row = quad*4 + reg
            float v = acc[r] + bo;
            if (ot < 16) {
                _Float16 hf = (_Float16)v;
                projf[(size_t)(b * 4096 + n) * 256 + o] = *(ushort_t*)&hf;
            } else {
                gT[(size_t)(b * 128 + (o - 256)) * 4096 + n] = f2b(v);
            }
        }
    }
}

// ============================================================================
// Kernel 3: flash, templated on KVB (keys per tile). 256 threads, 4 waves x
// 32 q-rows. 32x32x16 MFMA, swapped S (P^T in-register), permlane exchange,
// XCD combo swizzle. KVB=64 / KQ<=4 (R18-exact structure). R21: opart stores
// are NON-TEMPORAL (single consumer, cross-XCD -> keep L2 clean for K/V).
// ============================================================================
template<int KVB>
__global__ __launch_bounds__(256, (KVB == 32 ? 4 : 2))
void flash_k(const ushort_t* __restrict__ projf,
             const ushort_t* __restrict__ gT,
             float* __restrict__ opart,
             float* __restrict__ oml,
             int kqlog) {
    constexpr int NT2 = KVB / 32;        // 32-key S-tiles per iter
    constexpr int NCH = KVB / 4;         // 1KB staging chunks per array
    constexpr int NPT = NCH / 4;         // chunks per thread per array
    __shared__ __align__(16) ushort_t KsF[2][KVB * 128];  // fp16 K, frag-order
    __shared__ __align__(16) ushort_t VsF[2][KVB * 128];  // bf16 V, frag-order

    int L = blockIdx.x;
    int xcd = L & 7, t = L >> 3;
    int c, j;
    if (kqlog >= 2)      { c = (t >> 5) * 8 + xcd; j = t & 31; }   // 16 combos
    else if (kqlog == 1) { c = xcd;                j = t; }
    else                 { c = xcd & 3;            j = t + ((xcd >> 2) << 4); }
    int b  = c >> kqlog;
    int kq = c & ((1 << kqlog) - 1);
    int q0 = j * 128;
    int iters = (4096 >> kqlog) / KVB;
    int kt0 = kq * iters;
    int tid = threadIdx.x, w = tid >> 6, lane = tid & 63;
    int ln = lane & 31, hh = lane >> 5;

    // staging: NCH chunks of 64x16B per array; wave w owns chunks w+4i.
    const ushort_t* kSrc[NPT];
    const ushort_t* vSrc[NPT];
    {
        int kb0 = kt0 * KVB;
        #pragma unroll
        for (int i = 0; i < NPT; i++) {
            int cc = w + i * 4;
            int t2 = cc >> 3, kk = cc & 7;
            kSrc[i] = projf + (size_t)(b * 4096 + kb0 + t2 * 32 + ln) * 256 + 128 + kk * 16 + hh * 8;
            int it = cc / (2 * NT2), g = cc % (2 * NT2);
            vSrc[i] = gT + (size_t)(b * 128 + it * 32 + ln) * 4096 + kb0 + g * 16 + hh * 8;
        }
    }

    // Q B-frags: B[ic=16*kk+8*hh+j][q=q0+32*w+ln]
    half8 qf[8];
    {
        const ushort_t* qp = projf + (size_t)(b * 4096 + q0 + w * 32 + ln) * 256 + hh * 8;
        #pragma unroll
        for (int kk = 0; kk < 8; kk++)
            qf[kk] = *(const half8*)(qp + kk * 16);
    }

    floatx16 oacc[4];
    #pragma unroll
    for (int it = 0; it < 4; it++)
        #pragma unroll
        for (int jj = 0; jj < 16; jj++) oacc[it][jj] = 0.f;
    float lacc[NT2];
    #pragma unroll
    for (int t2 = 0; t2 < NT2; t2++) lacc[t2] = 0.f;

    // prologue: stage kt0 into buf 0
    #pragma unroll
    for (int i = 0; i < NPT; i++) {
        int cc = w + i * 4;
        glds16(kSrc[i], &KsF[0][cc * 512]);
        glds16(vSrc[i], &VsF[0][cc * 512]);
        kSrc[i] += (size_t)KVB * 256;
        vSrc[i] += KVB;
    }

    for (int kt = kt0; kt < kt0 + iters; kt++) {
        int cur = (kt - kt0) & 1;
        __syncthreads();                             // publishes buf[cur] (vmcnt drain)
        if (kt + 1 < kt0 + iters) {                  // prefetch next into buf[1-cur]
            #pragma unroll
            for (int i = 0; i < NPT; i++) {
                int cc = w + i * 4;
                glds16(kSrc[i], &KsF[1 - cur][cc * 512]);
                glds16(vSrc[i], &VsF[1 - cur][cc * 512]);
                kSrc[i] += (size_t)KVB * 256;
                vSrc[i] += KVB;
            }
        }

        // S: NT2 independent accumulator chains, interleaved issue
        floatx16 sacc[NT2];
        #pragma unroll
        for (int t2 = 0; t2 < NT2; t2++)
            #pragma unroll
            for (int jj = 0; jj < 16; jj++) sacc[t2][jj] = 0.f;
        __builtin_amdgcn_s_setprio(1);
        #pragma unroll
        for (int kk = 0; kk < 8; kk++) {
            #pragma unroll
            for (int t2 = 0; t2 < NT2; t2++) {
                half8 ah = *(const half8*)&KsF[cur][((t2 * 8 + kk) * 64 + lane) * 8];
                sacc[t2] = __builtin_amdgcn_mfma_f32_32x32x16_f16(ah, qf[kk], sacc[t2], 0, 0, 0);
            }
        }
        __builtin_amdgcn_s_setprio(0);

        // fixed-shift softmax p = e^(S-64); tree-summed l; pack to bf16 frags
        short8 fr[2 * NT2];
        #pragma unroll
        for (int t2 = 0; t2 < NT2; t2++) {
            float ps[16];
            #pragma unroll
            for (int r = 0; r < 16; r++)
                ps[r] = __builtin_exp2f(fmaf(sacc[t2][r], 1.44269504f, -92.332481f));
            lacc[t2] += ((((ps[0] + ps[1]) + (ps[2] + ps[3]))
                        + ((ps[4] + ps[5]) + (ps[6] + ps[7])))
                       + (((ps[8] + ps[9]) + (ps[10] + ps[11]))
                        + ((ps[12] + ps[13]) + (ps[14] + ps[15]))));
            unsigned int pw[8];
            #pragma unroll
            for (int c2 = 0; c2 < 8; c2++) pw[c2] = pack2bf(ps[2 * c2], ps[2 * c2 + 1]);
            pl32swap(pw[0], pw[2]);
            pl32swap(pw[1], pw[3]);
            pl32swap(pw[4], pw[6]);
            pl32swap(pw[5], pw[7]);
            union { unsigned int u[4]; short8 s8; } fA, fB;
            fA.u[0] = pw[0]; fA.u[1] = pw[1]; fA.u[2] = pw[2]; fA.u[3] = pw[3];
            fB.u[0] = pw[4]; fB.u[1] = pw[5]; fB.u[2] = pw[6]; fB.u[3] = pw[7];
            fr[t2 * 2]     = fA.s8;
            fr[t2 * 2 + 1] = fB.s8;
        }

        // O += P.V: 4 independent oacc chains
        __builtin_amdgcn_s_setprio(1);
        #pragma unroll
        for (int it = 0; it < 4; it++) {
            #pragma unroll
            for (int kg = 0; kg < 2 * NT2; kg++) {
                short8 vv = *(const short8*)&VsF[cur][((it * 2 * NT2 + kg) * 64 + lane) * 8];
                oacc[it] = __builtin_amdgcn_mfma_f32_32x32x16_bf16(fr[kg], vv, oacc[it], 0, 0, 0);
            }
        }
        __builtin_amdgcn_s_setprio(0);
    }

    // epilogue: raw partial O (common exp shift, non-temporal) + l
    {
        int rowBase = b * 4096 + q0 + w * 32 + hh * 4;
        #pragma unroll
        for (int it = 0; it < 4; it++)
            #pragma unroll
            for (int r = 0; r < 16; r++) {
                int qrow = rowBase + (r & 3) + 8 * (r >> 2);
                __builtin_nontemporal_store(oacc[it][r],
                    opart + ((size_t)kq * 16384 + qrow) * 128 + it * 32 + ln);
            }
    }
    float lsum = lacc[0];
    #pragma unroll
    for (int t2 = 1; t2 < NT2; t2++) lsum += lacc[t2];
    lsum += __shfl_xor(lsum, 32, 64);                // join h=0/h=1 key halves
    if (lane < 32)
        oml[kq * 16384 + b * 4096 + q0 + w * 32 + lane] = lsum;
}

// ============================================================================
// Kernel 4: wy = w_w . y2^T + w_b, fused KQ-merge (templated KQ) + per-block
// stats partials (mrow-shfl tree -> contention-free part[co][1024]).
// R21: opart merge loads are NON-TEMPORAL (single use; keep weights/wy hot).
// ============================================================================
template<int KQ>
__global__ __launch_bounds__(256) void wy_k(const float* __restrict__ opart,
                                            const float* __restrict__ oml,
                                            const ushort_t* __restrict__ wwbh,
                                            const ushort_t* __restrict__ wwbl,
                                            const float* __restrict__ w_b,
                                            ushort_t* __restrict__ wy,
                                            float* __restrict__ part) {
    int b = blockIdx.y, n0 = blockIdx.x * 32;
    int tid = threadIdx.x, w = tid >> 6, lane = tid & 63;
    int mrow = lane & 15, quad = lane >> 4, koff = quad * 8;
    int half = w & 1, sect = w >> 1;
    int Rn = b * 4096 + n0 + half * 16 + mrow;

    float L = 0.f;
    #pragma unroll
    for (int kq = 0; kq < KQ; kq++) L += oml[kq * 16384 + Rn];
    float invL = 1.f / L;

    short8 bfh[4], bfl[4];
    #pragma unroll
    for (int kk = 0; kk < 4; kk++) {
        float a[8];
        #pragma unroll
        for (int j = 0; j < 8; j++) a[j] = 0.f;
        #pragma unroll
        for (int kq = 0; kq < KQ; kq++) {
            const float* p = opart + ((size_t)kq * 16384 + Rn) * 128 + kk * 32 + koff;
            float4v v0 = __builtin_nontemporal_load((const float4v*)p);
            float4v v1 = __builtin_nontemporal_load((const float4v*)(p + 4));
            #pragma unroll
            for (int j = 0; j < 4; j++) { a[j] += v0[j]; a[4 + j] += v1[j]; }
        }
        #pragma unroll
        for (int j = 0; j < 8; j++) {
            ushort_t h, l;
            split2(a[j] * invL, h, l);
            bfh[kk][j] = (short)h; bfl[kk][j] = (short)l;
        }
    }

    int coln = n0 + half * 16 + mrow;
    int pcol = (blockIdx.x * 4 + b) * 2 + half;      // 0..1023
    for (int cot = sect * 8; cot < sect * 8 + 8; cot++) {
        float4v acc = {0.f, 0.f, 0.f, 0.f};
        #pragma unroll
        for (int kk = 0; kk < 4; kk++) {
            size_t woff = (size_t)(cot * 16 + mrow) * 128 + kk * 32 + koff;
            short8 ah = *(const short8*)(wwbh + woff);
            short8 al = *(const short8*)(wwbl + woff);
            acc = __builtin_amdgcn_mfma_f32_16x16x32_bf16(ah, bfh[kk], acc, 0, 0, 0);
            acc = __builtin_amdgcn_mfma_f32_16x16x32_bf16(ah, bfl[kk], acc, 0, 0, 0);
            acc = __builtin_amdgcn_mfma_f32_16x16x32_bf16(al, bfh[kk], acc, 0, 0, 0);
        }
        float s1v[4], s2v[4];
        #pragma unroll
        for (int r = 0; r < 4; r++) {
            int co = cot * 16 + quad * 4 + r;
            ushort_t bv = f2b(acc[r] + w_b[co]);
            wy[(size_t)(b * 256 + co) * 4096 + coln] = bv;
            float vb = b2f(bv);                      // stored (rounded) value
            s1v[r] = vb; s2v[r] = vb * vb;
        }
        #pragma unroll
        for (int d = 1; d < 16; d <<= 1) {
            #pragma unroll
            for (int r = 0; r < 4; r++) {
                s1v[r] += __shfl_xor(s1v[r], d, 64);
                s2v[r] += __shfl_xor(s2v[r], d, 64);
            }
        }
        if (mrow == 0) {
            #pragma unroll
            for (int r = 0; r < 4; r++) {
                int co = cot * 16 + quad * 4 + r;
                part[co * 1024 + pcol]          = s1v[r];
                part[262144 + co * 1024 + pcol] = s2v[r];
            }
        }
    }
}

// ============================================================================
// Kernel 5: BN (batch stats from partials, biased var, eps=1e-5) + residual.
// Each block serves one channel: reduce its 1024 (sum,sumsq) partials, then
// normalize + add x. R21: nt load for x (single use), nt store for out.
// ============================================================================
__global__ __launch_bounds__(256) void bn_k(const ushort_t* __restrict__ wy,
                                            const float* __restrict__ x,
                                            const float* __restrict__ gamma,
                                            const float* __restrict__ beta,
                                            const float* __restrict__ part,
                                            float* __restrict__ out) {
    __shared__ float red[8];
    __shared__ float sc[2];
    int tid = threadIdx.x, w = tid >> 6, lane = tid & 63;
    int idx = (blockIdx.x * 256 + tid) * 8;             // B*C*N = 1<<22
    int c = (idx >> 12) & 255;                          // one channel per block

    float4v p1 = *(const float4v*)(part + c * 1024 + tid * 4);
    float4v p2 = *(const float4v*)(part + 262144 + c * 1024 + tid * 4);
    float s  = (p1[0] + p1[1]) + (p1[2] + p1[3]);
    float s2 = (p2[0] + p2[1]) + (p2[2] + p2[3]);
    #pragma unroll
    for (int d = 1; d < 64; d <<= 1) { s += __shfl_xor(s, d, 64); s2 += __shfl_xor(s2, d, 64); }
    if (lane == 0) { red[w] = s; red[4 + w] = s2; }
    __syncthreads();
    if (tid == 0) {
        float S  = (red[0] + red[1]) + (red[2] + red[3]);
        float S2 = (red[4] + red[5]) + (red[6] + red[7]);
        const float inv_cnt = 1.f / 16384.f;
        float mean = S * inv_cnt;
        float var  = S2 * inv_cnt - mean * mean;
        float inv  = rsqrtf(var + 1e-5f);
        float scale = gamma[c] * inv;
        sc[0] = scale;
        sc[1] = beta[c] - mean * scale;
    }
    __syncthreads();
    float scale = sc[0], shift = sc[1];

    ushort8 wv = *(const ushort8*)(wy + idx);
    float4v x0 = __builtin_nontemporal_load((const float4v*)(x + idx));
    float4v x1 = __builtin_nontemporal_load((const float4v*)(x + idx + 4));
    float4v o0, o1;
    #pragma unroll
    for (int j = 0; j < 4; j++) {
        o0[j] = b2f(wv[j]) * scale + shift + x0[j];
        o1[j] = b2f(wv[4 + j]) * scale + shift + x1[j];
    }
    __builtin_nontemporal_store(o0, (float4v*)(out + idx));
    __builtin_nontemporal_store(o1, (float4v*)(out + idx + 4));
}

extern "C" void kernel_launch(void* const* d_in, const int* in_sizes, int n_in,
                              void* d_out, int out_size, void* d_ws, size_t ws_size,
                              hipStream_t stream) {
    const float* x    = (const float*)d_in[0];
    const float* y    = (const float*)d_in[1];
    const float* g_w  = (const float*)d_in[2];
    const float* g_b  = (const float*)d_in[3];
    const float* dx_w = (const float*)d_in[4];
    const float* dx_b = (const float*)d_in[5];
    const float* dy_w = (const float*)d_in[6];
    const float* dy_b = (const float*)d_in[7];
    const float* w_w  = (const float*)d_in[8];
    const float* w_b  = (const float*)d_in[9];
    const float* bn_g = (const float*)d_in[10];
    const float* bn_b = (const float*)d_in[11];

    char* ws = (char*)d_ws;
    ushort_t* wtfh  = (ushort_t*)(ws + WTFH_OFF);
    ushort_t* wtfl  = (ushort_t*)(ws + WTFL_OFF);
    ushort_t* wwbh  = (ushort_t*)(ws + WWBH_OFF);
    ushort_t* wwbl  = (ushort_t*)(ws + WWBL_OFF);
    float*    bias  = (float*)(ws + BIAS_OFF);
    ushort_t* projf = (ushort_t*)(ws + PROJF_OFF);
    ushort_t* gT    = (ushort_t*)(ws + GT_OFF);
    float*    opart = (float*)(ws + OPART_OFF);
    ushort_t* wy    = (ushort_t*)(ws + WY_OFF);   // reuses projf (dead after flash)
    float*    part  = (float*)(ws + PART_OFF);    // reuses gT (dead after flash)
    float*    out   = (float*)d_out;

    // ws-adaptive K-split: KQ=4 -> 512 flash blocks = 2 blocks/CU (best
    // measured geometry; KQ=8/KVB=32 regressed — R13 post-mortem).
    int kqlog;
    if      (ws_size >= 13631488u + 4u * (8388608u + 65536u)) kqlog = 2;
    else if (ws_size >= 13631488u + 2u * (8388608u + 65536u)) kqlog = 1;
    else                                                      kqlog = 0;
    int KQ = 1 << kqlog;
    float* oml = (float*)(ws + OPART_OFF + (size_t)KQ * 8388608u);

    prep_k<<<384, 256, 0, stream>>>(dx_w, dy_w, g_w, dx_b, dy_b, g_b, w_w,
                                    wtfh, wtfl, wwbh, wwbl, bias);
    proj_k<<<dim3(128, 4, 2), 256, 0, stream>>>(x, y, wtfh, wtfl, bias, projf, gT);
    flash_k<64><<<dim3(128 << kqlog), 256, 0, stream>>>(projf, gT, opart, oml, kqlog);
    if (KQ == 4)
        wy_k<4><<<dim3(128, 4), 256, 0, stream>>>(opart, oml, wwbh, wwbl, w_b, wy, part);
    else if (KQ == 2)
        wy_k<2><<<dim3(128, 4), 256, 0, stream>>>(opart, oml, wwbh, wwbl, w_b, wy, part);
    else
        wy_k<1><<<dim3(128, 4), 256, 0, stream>>>(opart, oml, wwbh, wwbl, w_b, wy, part);
    bn_k<<<2048, 256, 0, stream>>>(wy, x, bn_g, bn_b, part, out);
}

// Round 14
// 204.797 us; speedup vs baseline: 1.0336x; 1.0336x over previous
//
#include <hip/hip_runtime.h>
#include <hip/hip_bf16.h>
#include <math.h>

// Problem: B=4, C=256, H=W=64 (N=4096), IC=128. I/O float32.
// R22: restore R20-exact (best measured: 207.1us). R21's nontemporal hints
//     REVERTED — nt bypasses L2 on CDNA, so flash's opart stores stopped
//     landing in L2 and wy's merge reads went to HBM: −4.6us net (falsifier
//     fired; cross-XCD writeback theory dead). Configuration summary:
//     5 dispatches; flash 4-wave KQ=4/KVB=64 (60us floor, defended vs 7
//     attacks); proj blockIdx.z source-split (4 blocks/CU); wy fused KQ-merge
//     + contention-free stats partials; bn reduces partials + normalizes.
typedef unsigned short ushort_t;
typedef __attribute__((ext_vector_type(8))) short     short8;   // bf16x8 MFMA frag
typedef __attribute__((ext_vector_type(8))) _Float16  half8;    // f16x8 MFMA frag
typedef __attribute__((ext_vector_type(8))) unsigned short ushort8;
typedef __attribute__((ext_vector_type(4))) float     float4v;
typedef __attribute__((ext_vector_type(16))) float    floatx16; // 32x32 acc

__device__ __forceinline__ float b2f(ushort_t u) {
    return __uint_as_float(((unsigned)u) << 16);
}
__device__ __forceinline__ ushort_t f2b(float f) {
    unsigned i = __float_as_uint(f);
    return (ushort_t)((i + 0x7FFFu + ((i >> 16) & 1u)) >> 16);  // RNE
}
__device__ __forceinline__ void split2(float v, ushort_t& h, ushort_t& l) {
    h = f2b(v);
    l = f2b(v - b2f(h));   // combined rel err ~2^-17
}
__device__ __forceinline__ void glds16(const ushort_t* g, ushort_t* l) {
    __builtin_amdgcn_global_load_lds((const __attribute__((address_space(1))) void*)g,
                                     (__attribute__((address_space(3))) void*)l, 16, 0, 0);
}
__device__ __forceinline__ unsigned int pack2bf(float lo, float hi) {
    unsigned int r;
    asm("v_cvt_pk_bf16_f32 %0, %1, %2" : "=v"(r) : "v"(lo), "v"(hi));
    return r;
}
// v_permlane32_swap_b32: a[32+i] <-> b[i]. After: a=[a.lo, b.lo_old], b=[a.hi_old, b.hi]
__device__ __forceinline__ void pl32swap(unsigned int& a, unsigned int& b) {
    asm("v_permlane32_swap_b32 %0, %1" : "+v"(a), "+v"(b));
}

// ---- workspace layout (bytes) ----
#define WTFH_OFF   0            // 192 KB proj weights B-frag hi
#define WTFL_OFF   196608       // 192 KB lo
#define WWBH_OFF   393216       // 64 KB w_w bf16 hi
#define WWBL_OFF   458752       // 64 KB lo
#define BIAS_OFF   524288       // 384 f32
#define PROJF_OFF  1048576      // 8 MB fp16 (theta|phi) [b][n][256]
#define GT_OFF     9437184      // 4 MB bf16 g transposed [b][ic][n]
#define OPART_OFF  13631488     // KQ*8 MB f32 partial O; oml after
#define WY_OFF     1048576      // wy bf16 reuses projf region (dead after flash)
#define PART_OFF   9437184      // 2 MB stats partials reuse gT region (dead after flash)

__global__ void prep_k(const float* __restrict__ dx_w, const float* __restrict__ dy_w,
                       const float* __restrict__ g_w,  const float* __restrict__ dx_b,
                       const float* __restrict__ dy_b, const float* __restrict__ g_b,
                       const float* __restrict__ w_w,
                       ushort_t* __restrict__ wtfh, ushort_t* __restrict__ wtfl,
                       ushort_t* __restrict__ wwbh, ushort_t* __restrict__ wwbl,
                       float* __restrict__ bias) {
    int idx = blockIdx.x * 256 + threadIdx.x;          // 0..98303
    int j = idx & 7, lane = (idx >> 3) & 63, kk = (idx >> 9) & 7, ot = idx >> 12;
    int o = ot * 16 + (lane & 15);
    int c = kk * 32 + ((lane >> 4) * 8) + j;
    float v;
    if (o < 128)      v = dx_w[o * 256 + c];
    else if (o < 256) v = dy_w[(o - 128) * 256 + c];
    else              v = g_w[(o - 256) * 256 + c];
    ushort_t h, l;
    split2(v, h, l);
    wtfh[idx] = h; wtfl[idx] = l;
    if (idx < 32768) {                                 // w_w [256][128]
        split2(w_w[idx], h, l);
        wwbh[idx] = h; wwbl[idx] = l;
    }
    if (idx < 384) {
        bias[idx] = (idx < 128) ? dx_b[idx]
                  : (idx < 256) ? dy_b[idx - 128]
                                : g_b[idx - 256];
    }
}

// ============================================================================
// Kernel 2: projections. s (source select) on blockIdx.z — grid 128x4x2, 1024
// blocks, 4 blocks/CU (33KB LDS). Each block: stage its source tile ->
// barrier -> MFMA. xT row stride 258 breaks ds_write_b16 bank conflicts.
// ============================================================================
#define XTS 258
__global__ __launch_bounds__(256) void proj_k(const float* __restrict__ x,
                                              const float* __restrict__ y,
                                              const ushort_t* __restrict__ wtfh,
                                              const ushort_t* __restrict__ wtfl,
                                              const float* __restrict__ bias,
                                              ushort_t* __restrict__ projf,
                                              ushort_t* __restrict__ gT) {
    __shared__ ushort_t xT[2][32 * XTS];   // [hi/lo][n][c], ~33KB
    int b = blockIdx.y, n0 = blockIdx.x * 32;
    int s = blockIdx.z;
    int tid = threadIdx.x;
    int w = tid >> 6, lane = tid & 63;
    int mrow = lane & 15, quad = lane >> 4, koff = quad * 8;
    int half = w & 1, sect = w >> 1;
    int arow = half * 16 + mrow;

    const float* src = s ? y : x;
    #pragma unroll
    for (int i = 0; i < 4; i++) {
        int ch = tid + i * 256;
        int c = ch >> 2, off = (ch & 3) * 8;
        const float* p = src + (size_t)(b * 256 + c) * 4096 + n0 + off;
        float4v v0 = *(const float4v*)p;
        float4v v1 = *(const float4v*)(p + 4);
        #pragma unroll
        for (int jj = 0; jj < 4; jj++) {
            ushort_t h, l;
            split2(v0[jj], h, l);
            xT[0][(off + jj) * XTS + c] = h;
            xT[1][(off + jj) * XTS + c] = l;
            split2(v1[jj], h, l);
            xT[0][(off + 4 + jj) * XTS + c] = h;
            xT[1][(off + 4 + jj) * XTS + c] = l;
        }
    }
    __syncthreads();

    short8 fh[8], fl[8];
    #pragma unroll
    for (int kk = 0; kk < 8; kk++) {
        fh[kk] = *(const short8*)&xT[0][arow * XTS + kk * 32 + koff];
        fl[kk] = *(const short8*)&xT[1][arow * XTS + kk * 32 + koff];
    }

    int ot0 = s ? (8 + sect * 8) : (sect * 4);
    int ot1 = s ? (ot0 + 8) : (ot0 + 4);
    for (int ot = ot0; ot < ot1; ot++) {
        float4v acc = {0.f, 0.f, 0.f, 0.f};
        #pragma unroll
        for (int kk = 0; kk < 8; kk++) {
            short8 bh = *(const short8*)(wtfh + (size_t)((ot * 8 + kk) * 64 + lane) * 8);
            short8 bl = *(const short8*)(wtfl + (size_t)((ot * 8 + kk) * 64 + lane) * 8);
            acc = __builtin_amdgcn_mfma_f32_16x16x32_bf16(fh[kk], bh, acc, 0, 0, 0);
            acc = __builtin_amdgcn_mfma_f32_16x16x32_bf16(fh[kk], bl, acc, 0, 0, 0);
            acc = __builtin_amdgcn_mfma_f32_16x16x32_bf16(fl[kk], bh, acc, 0, 0, 0);
        }
        int o = ot * 16 + mrow;                  // C/D: col = lane&15
        float bo = bias[o];
        #pragma unroll
        for (int r = 0; r < 4; r++) {
            int n = n0 + half * 16 + quad * 4 + r;  // C/D: row = quad*4 + reg
            float v = acc[r] + bo;
            if (ot < 16) {
                _Float16 hf = (_Float16)v;
                projf[(size_t)(b * 4096 + n) * 256 + o] = *(ushort_t*)&hf;
            } else {
                gT[(size_t)(b * 128 + (o - 256)) * 4096 + n] = f2b(v);
            }
        }
    }
}

// ============================================================================
// Kernel 3: flash, templated on KVB (keys per tile). 256 threads, 4 waves x
// 32 q-rows. 32x32x16 MFMA, swapped S (P^T in-register), permlane exchange,
// XCD combo swizzle. KVB=64 / KQ<=4 (best measured; R13/R19 occupancy probes
// both regressed — flash is structurally bound at ~60us here).
// ============================================================================
template<int KVB>
__global__ __launch_bounds__(256, (KVB == 32 ? 4 : 2))
void flash_k(const ushort_t* __restrict__ projf,
             const ushort_t* __restrict__ gT,
             float* __restrict__ opart,
             float* __restrict__ oml,
             int kqlog) {
    constexpr int NT2 = KVB / 32;        // 32-key S-tiles per iter
    constexpr int NCH = KVB / 4;         // 1KB staging chunks per array
    constexpr int NPT = NCH / 4;         // chunks per thread per array
    __shared__ __align__(16) ushort_t KsF[2][KVB * 128];  // fp16 K, frag-order
    __shared__ __align__(16) ushort_t VsF[2][KVB * 128];  // bf16 V, frag-order

    int L = blockIdx.x;
    int xcd = L & 7, t = L >> 3;
    int c, j;
    if (kqlog >= 2)      { c = (t >> 5) * 8 + xcd; j = t & 31; }   // 16 combos
    else if (kqlog == 1) { c = xcd;                j = t; }
    else                 { c = xcd & 3;            j = t + ((xcd >> 2) << 4); }
    int b  = c >> kqlog;
    int kq = c & ((1 << kqlog) - 1);
    int q0 = j * 128;
    int iters = (4096 >> kqlog) / KVB;
    int kt0 = kq * iters;
    int tid = threadIdx.x, w = tid >> 6, lane = tid & 63;
    int ln = lane & 31, hh = lane >> 5;

    // staging: NCH chunks of 64x16B per array; wave w owns chunks w+4i.
    const ushort_t* kSrc[NPT];
    const ushort_t* vSrc[NPT];
    {
        int kb0 = kt0 * KVB;
        #pragma unroll
        for (int i = 0; i < NPT; i++) {
            int cc = w + i * 4;
            int t2 = cc >> 3, kk = cc & 7;
            kSrc[i] = projf + (size_t)(b * 4096 + kb0 + t2 * 32 + ln) * 256 + 128 + kk * 16 + hh * 8;
            int it = cc / (2 * NT2), g = cc % (2 * NT2);
            vSrc[i] = gT + (size_t)(b * 128 + it * 32 + ln) * 4096 + kb0 + g * 16 + hh * 8;
        }
    }

    // Q B-frags: B[ic=16*kk+8*hh+j][q=q0+32*w+ln]
    half8 qf[8];
    {
        const ushort_t* qp = projf + (size_t)(b * 4096 + q0 + w * 32 + ln) * 256 + hh * 8;
        #pragma unroll
        for (int kk = 0; kk < 8; kk++)
            qf[kk] = *(const half8*)(qp + kk * 16);
    }

    floatx16 oacc[4];
    #pragma unroll
    for (int it = 0; it < 4; it++)
        #pragma unroll
        for (int jj = 0; jj < 16; jj++) oacc[it][jj] = 0.f;
    float lacc[NT2];
    #pragma unroll
    for (int t2 = 0; t2 < NT2; t2++) lacc[t2] = 0.f;

    // prologue: stage kt0 into buf 0
    #pragma unroll
    for (int i = 0; i < NPT; i++) {
        int cc = w + i * 4;
        glds16(kSrc[i], &KsF[0][cc * 512]);
        glds16(vSrc[i], &VsF[0][cc * 512]);
        kSrc[i] += (size_t)KVB * 256;
        vSrc[i] += KVB;
    }

    for (int kt = kt0; kt < kt0 + iters; kt++) {
        int cur = (kt - kt0) & 1;
        __syncthreads();                             // publishes buf[cur] (vmcnt drain)
        if (kt + 1 < kt0 + iters) {                  // prefetch next into buf[1-cur]
            #pragma unroll
            for (int i = 0; i < NPT; i++) {
                int cc = w + i * 4;
                glds16(kSrc[i], &KsF[1 - cur][cc * 512]);
                glds16(vSrc[i], &VsF[1 - cur][cc * 512]);
                kSrc[i] += (size_t)KVB * 256;
                vSrc[i] += KVB;
            }
        }

        // S: NT2 independent accumulator chains, interleaved issue
        floatx16 sacc[NT2];
        #pragma unroll
        for (int t2 = 0; t2 < NT2; t2++)
            #pragma unroll
            for (int jj = 0; jj < 16; jj++) sacc[t2][jj] = 0.f;
        __builtin_amdgcn_s_setprio(1);
        #pragma unroll
        for (int kk = 0; kk < 8; kk++) {
            #pragma unroll
            for (int t2 = 0; t2 < NT2; t2++) {
                half8 ah = *(const half8*)&KsF[cur][((t2 * 8 + kk) * 64 + lane) * 8];
                sacc[t2] = __builtin_amdgcn_mfma_f32_32x32x16_f16(ah, qf[kk], sacc[t2], 0, 0, 0);
            }
        }
        __builtin_amdgcn_s_setprio(0);

        // fixed-shift softmax p = e^(S-64); tree-summed l; pack to bf16 frags
        short8 fr[2 * NT2];
        #pragma unroll
        for (int t2 = 0; t2 < NT2; t2++) {
            float ps[16];
            #pragma unroll
            for (int r = 0; r < 16; r++)
                ps[r] = __builtin_exp2f(fmaf(sacc[t2][r], 1.44269504f, -92.332481f));
            lacc[t2] += ((((ps[0] + ps[1]) + (ps[2] + ps[3]))
                        + ((ps[4] + ps[5]) + (ps[6] + ps[7])))
                       + (((ps[8] + ps[9]) + (ps[10] + ps[11]))
                        + ((ps[12] + ps[13]) + (ps[14] + ps[15]))));
            unsigned int pw[8];
            #pragma unroll
            for (int c2 = 0; c2 < 8; c2++) pw[c2] = pack2bf(ps[2 * c2], ps[2 * c2 + 1]);
            pl32swap(pw[0], pw[2]);
            pl32swap(pw[1], pw[3]);
            pl32swap(pw[4], pw[6]);
            pl32swap(pw[5], pw[7]);
            union { unsigned int u[4]; short8 s8; } fA, fB;
            fA.u[0] = pw[0]; fA.u[1] = pw[1]; fA.u[2] = pw[2]; fA.u[3] = pw[3];
            fB.u[0] = pw[4]; fB.u[1] = pw[5]; fB.u[2] = pw[6]; fB.u[3] = pw[7];
            fr[t2 * 2]     = fA.s8;
            fr[t2 * 2 + 1] = fB.s8;
        }

        // O += P.V: 4 independent oacc chains
        __builtin_amdgcn_s_setprio(1);
        #pragma unroll
        for (int it = 0; it < 4; it++) {
            #pragma unroll
            for (int kg = 0; kg < 2 * NT2; kg++) {
                short8 vv = *(const short8*)&VsF[cur][((it * 2 * NT2 + kg) * 64 + lane) * 8];
                oacc[it] = __builtin_amdgcn_mfma_f32_32x32x16_bf16(fr[kg], vv, oacc[it], 0, 0, 0);
            }
        }
        __builtin_amdgcn_s_setprio(0);
    }

    // epilogue: raw partial O (common exp shift) + l
    {
        int rowBase = b * 4096 + q0 + w * 32 + hh * 4;
        #pragma unroll
        for (int it = 0; it < 4; it++)
            #pragma unroll
            for (int r = 0; r < 16; r++) {
                int qrow = rowBase + (r & 3) + 8 * (r >> 2);
                opart[((size_t)kq * 16384 + qrow) * 128 + it * 32 + ln] = oacc[it][r];
            }
    }
    float lsum = lacc[0];
    #pragma unroll
    for (int t2 = 1; t2 < NT2; t2++) lsum += lacc[t2];
    lsum += __shfl_xor(lsum, 32, 64);                // join h=0/h=1 key halves
    if (lane < 32)
        oml[kq * 16384 + b * 4096 + q0 + w * 32 + lane] = lsum;
}

// ============================================================================
// Kernel 4: wy = w_w . y2^T + w_b, fused KQ-merge (templated KQ) + per-block
// stats partials: mrow-shfl tree reduces each channel's 16 columns per wave;
// mrow==0 lanes store (sum, sumsq) to part[co][1024] (contention-free).
// Uses bf16-rounded stored values.
// ============================================================================
template<int KQ>
__global__ __launch_bounds__(256) void wy_k(const float* __restrict__ opart,
                                            const float* __restrict__ oml,
                                            const ushort_t* __restrict__ wwbh,
                                            const ushort_t* __restrict__ wwbl,
                                            const float* __restrict__ w_b,
                                            ushort_t* __restrict__ wy,
                                            float* __restrict__ part) {
    int b = blockIdx.y, n0 = blockIdx.x * 32;
    int tid = threadIdx.x, w = tid >> 6, lane = tid & 63;
    int mrow = lane & 15, quad = lane >> 4, koff = quad * 8;
    int half = w & 1, sect = w >> 1;
    int Rn = b * 4096 + n0 + half * 16 + mrow;

    float L = 0.f;
    #pragma unroll
    for (int kq = 0; kq < KQ; kq++) L += oml[kq * 16384 + Rn];
    float invL = 1.f / L;

    short8 bfh[4], bfl[4];
    #pragma unroll
    for (int kk = 0; kk < 4; kk++) {
        float a[8];
        #pragma unroll
        for (int j = 0; j < 8; j++) a[j] = 0.f;
        #pragma unroll
        for (int kq = 0; kq < KQ; kq++) {
            const float* p = opart + ((size_t)kq * 16384 + Rn) * 128 + kk * 32 + koff;
            float4v v0 = *(const float4v*)p;
            float4v v1 = *(const float4v*)(p + 4);
            #pragma unroll
            for (int j = 0; j < 4; j++) { a[j] += v0[j]; a[4 + j] += v1[j]; }
        }
        #pragma unroll
        for (int j = 0; j < 8; j++) {
            ushort_t h, l;
            split2(a[j] * invL, h, l);
            bfh[kk][j] = (short)h; bfl[kk][j] = (short)l;
        }
    }

    int coln = n0 + half * 16 + mrow;
    int pcol = (blockIdx.x * 4 + b) * 2 + half;      // 0..1023
    for (int cot = sect * 8; cot < sect * 8 + 8; cot++) {
        float4v acc = {0.f, 0.f, 0.f, 0.f};
        #pragma unroll
        for (int kk = 0; kk < 4; kk++) {
            size_t woff = (size_t)(cot * 16 + mrow) * 128 + kk * 32 + koff;
            short8 ah = *(const short8*)(wwbh + woff);
            short8 al = *(const short8*)(wwbl + woff);
            acc = __builtin_amdgcn_mfma_f32_16x16x32_bf16(ah, bfh[kk], acc, 0, 0, 0);
            acc = __builtin_amdgcn_mfma_f32_16x16x32_bf16(ah, bfl[kk], acc, 0, 0, 0);
            acc = __builtin_amdgcn_mfma_f32_16x16x32_bf16(al, bfh[kk], acc, 0, 0, 0);
        }
        float s1v[4], s2v[4];
        #pragma unroll
        for (int r = 0; r < 4; r++) {
            int co = cot * 16 + quad * 4 + r;
            ushort_t bv = f2b(acc[r] + w_b[co]);
            wy[(size_t)(b * 256 + co) * 4096 + coln] = bv;
            float vb = b2f(bv);                      // stored (rounded) value
            s1v[r] = vb; s2v[r] = vb * vb;
        }
        #pragma unroll
        for (int d = 1; d < 16; d <<= 1) {
            #pragma unroll
            for (int r = 0; r < 4; r++) {
                s1v[r] += __shfl_xor(s1v[r], d, 64);
                s2v[r] += __shfl_xor(s2v[r], d, 64);
            }
        }
        if (mrow == 0) {
            #pragma unroll
            for (int r = 0; r < 4; r++) {
                int co = cot * 16 + quad * 4 + r;
                part[co * 1024 + pcol]          = s1v[r];
                part[262144 + co * 1024 + pcol] = s2v[r];
            }
        }
    }
}

// ============================================================================
// Kernel 5: BN (batch stats from partials, biased var, eps=1e-5) + residual.
// Each block serves one channel: reduce its 1024 (sum,sumsq) partials (8KB,
// L2-hot; 256 thr x float4 + shfl/LDS tree), then normalize + add x.
// ============================================================================
__global__ __launch_bounds__(256) void bn_k(const ushort_t* __restrict__ wy,
                                            const float* __restrict__ x,
                                            const float* __restrict__ gamma,
                                            const float* __restrict__ beta,
                                            const float* __restrict__ part,
                                            float* __restrict__ out) {
    __shared__ float red[8];
    __shared__ float sc[2];
    int tid = threadIdx.x, w = tid >> 6, lane = tid & 63;
    int idx = (blockIdx.x * 256 + tid) * 8;             // B*C*N = 1<<22
    int c = (idx >> 12) & 255;                          // one channel per block

    float4v p1 = *(const float4v*)(part + c * 1024 + tid * 4);
    float4v p2 = *(const float4v*)(part + 262144 + c * 1024 + tid * 4);
    float s  = (p1[0] + p1[1]) + (p1[2] + p1[3]);
    float s2 = (p2[0] + p2[1]) + (p2[2] + p2[3]);
    #pragma unroll
    for (int d = 1; d < 64; d <<= 1) { s += __shfl_xor(s, d, 64); s2 += __shfl_xor(s2, d, 64); }
    if (lane == 0) { red[w] = s; red[4 + w] = s2; }
    __syncthreads();
    if (tid == 0) {
        float S  = (red[0] + red[1]) + (red[2] + red[3]);
        float S2 = (red[4] + red[5]) + (red[6] + red[7]);
        const float inv_cnt = 1.f / 16384.f;
        float mean = S * inv_cnt;
        float var  = S2 * inv_cnt - mean * mean;
        float inv  = rsqrtf(var + 1e-5f);
        float scale = gamma[c] * inv;
        sc[0] = scale;
        sc[1] = beta[c] - mean * scale;
    }
    __syncthreads();
    float scale = sc[0], shift = sc[1];

    ushort8 wv = *(const ushort8*)(wy + idx);
    float4v x0 = *(const float4v*)(x + idx);
    float4v x1 = *(const float4v*)(x + idx + 4);
    float4v o0, o1;
    #pragma unroll
    for (int j = 0; j < 4; j++) {
        o0[j] = b2f(wv[j]) * scale + shift + x0[j];
        o1[j] = b2f(wv[4 + j]) * scale + shift + x1[j];
    }
    *(float4v*)(out + idx) = o0;
    *(float4v*)(out + idx + 4) = o1;
}

extern "C" void kernel_launch(void* const* d_in, const int* in_sizes, int n_in,
                              void* d_out, int out_size, void* d_ws, size_t ws_size,
                              hipStream_t stream) {
    const float* x    = (const float*)d_in[0];
    const float* y    = (const float*)d_in[1];
    const float* g_w  = (const float*)d_in[2];
    const float* g_b  = (const float*)d_in[3];
    const float* dx_w = (const float*)d_in[4];
    const float* dx_b = (const float*)d_in[5];
    const float* dy_w = (const float*)d_in[6];
    const float* dy_b = (const float*)d_in[7];
    const float* w_w  = (const float*)d_in[8];
    const float* w_b  = (const float*)d_in[9];
    const float* bn_g = (const float*)d_in[10];
    const float* bn_b = (const float*)d_in[11];

    char* ws = (char*)d_ws;
    ushort_t* wtfh  = (ushort_t*)(ws + WTFH_OFF);
    ushort_t* wtfl  = (ushort_t*)(ws + WTFL_OFF);
    ushort_t* wwbh  = (ushort_t*)(ws + WWBH_OFF);
    ushort_t* wwbl  = (ushort_t*)(ws + WWBL_OFF);
    float*    bias  = (float*)(ws + BIAS_OFF);
    ushort_t* projf = (ushort_t*)(ws + PROJF_OFF);
    ushort_t* gT    = (ushort_t*)(ws + GT_OFF);
    float*    opart = (float*)(ws + OPART_OFF);
    ushort_t* wy    = (ushort_t*)(ws + WY_OFF);   // reuses projf (dead after flash)
    float*    part  = (float*)(ws + PART_OFF);    // reuses gT (dead after flash)
    float*    out   = (float*)d_out;

    // ws-adaptive K-split: KQ=4 -> 512 flash blocks = 2 blocks/CU (best
    // measured geometry; KQ=8/KVB=32 regressed — R13 post-mortem).
    int kqlog;
    if      (ws_size >= 13631488u + 4u * (8388608u + 65536u)) kqlog = 2;
    else if (ws_size >= 13631488u + 2u * (8388608u + 65536u)) kqlog = 1;
    else                                                      kqlog = 0;
    int KQ = 1 << kqlog;
    float* oml = (float*)(ws + OPART_OFF + (size_t)KQ * 8388608u);

    prep_k<<<384, 256, 0, stream>>>(dx_w, dy_w, g_w, dx_b, dy_b, g_b, w_w,
                                    wtfh, wtfl, wwbh, wwbl, bias);
    proj_k<<<dim3(128, 4, 2), 256, 0, stream>>>(x, y, wtfh, wtfl, bias, projf, gT);
    flash_k<64><<<dim3(128 << kqlog), 256, 0, stream>>>(projf, gT, opart, oml, kqlog);
    if (KQ == 4)
        wy_k<4><<<dim3(128, 4), 256, 0, stream>>>(opart, oml, wwbh, wwbl, w_b, wy, part);
    else if (KQ == 2)
        wy_k<2><<<dim3(128, 4), 256, 0, stream>>>(opart, oml, wwbh, wwbl, w_b, wy, part);
    else
        wy_k<1><<<dim3(128, 4), 256, 0, stream>>>(opart, oml, wwbh, wwbl, w_b, wy, part);
    bn_k<<<2048, 256, 0, stream>>>(wy, x, bn_g, bn_b, part, out);
}